// Round 1
// baseline (1364.635 us; speedup 1.0000x reference)
//
#include <hip/hip_runtime.h>
#include <math.h>

#define B 16
#define T 8192
#define C 1024
#define H 16
#define D 64
#define NS 32   // t-chunks for weighted-sum pass

// ---------------------------------------------------------------------------
// Workspace layout (floats unless noted):
//   fdiv   : double[C]      div_term[c]/(2*pi), c's pair-index exponent
//   q      : B*C            first-token query per batch
//   rt     : B*C*H          r transposed to [b][c][h], scaled by 1/8
//   cc     : B*H            q.bk constant per (b,h), scaled by 1/8
//   scores : B*H*T
//   ml     : B*H*2          (max, 1/sum) per (b,h)
//   sacc   : B*H*C          softmax-weighted sum of x~ rows
//   y      : B*C            attention output before Wo
// total ~10.6 MB
// ---------------------------------------------------------------------------

__global__ void k_fdiv(double* __restrict__ fdiv) {
    int c = blockIdx.x * 256 + threadIdx.x;
    if (c < C) {
        int i2 = c & ~1;
        double e = exp((double)i2 * (-9.210340371976184 / 1024.0)); // -ln(10000)/C
        fdiv[c] = e * 0.15915494309189535;                          // * 1/(2pi)
    }
}

// q[b][c] = bq[c] + sum_k x~[b,0,k] * Wq[k][c];  PE(0,k) = (k odd ? 1 : 0)
__global__ void __launch_bounds__(256) k_q(const float* __restrict__ x,
                                           const float* __restrict__ Wq,
                                           const float* __restrict__ bq,
                                           float* __restrict__ q) {
    __shared__ float xs[C];
    int b = blockIdx.x >> 2;
    int cblk = blockIdx.x & 3;
    const float* xrow = x + (size_t)b * T * C;
    for (int i = threadIdx.x; i < C; i += 256)
        xs[i] = xrow[i] + ((i & 1) ? 1.0f : 0.0f);
    __syncthreads();
    int c = cblk * 256 + threadIdx.x;
    float acc = bq[c];
#pragma unroll 8
    for (int k = 0; k < C; ++k)
        acc += xs[k] * Wq[(size_t)k * C + c];
    q[b * C + c] = acc;
}

// rt[b][c][h] = 0.125 * sum_d Wkv[c][h*64+d] * q[b][h*64+d]
// cc[b][h]    = 0.125 * sum_d bkv[h*64+d]   * q[b][h*64+d]
__global__ void __launch_bounds__(256) k_rt(const float* __restrict__ Wkv,
                                            const float* __restrict__ bkv,
                                            const float* __restrict__ q,
                                            float* __restrict__ rt,
                                            float* __restrict__ cc) {
    __shared__ float qs[D];
    int b = blockIdx.x >> 4, h = blockIdx.x & 15;
    if (threadIdx.x < D) qs[threadIdx.x] = q[b * C + h * D + threadIdx.x];
    __syncthreads();
    for (int c = threadIdx.x; c < C; c += 256) {
        const float4* wrow = (const float4*)(Wkv + (size_t)c * (2 * C) + h * D);
        float acc = 0.f;
#pragma unroll
        for (int d4 = 0; d4 < D / 4; ++d4) {
            float4 w = wrow[d4];
            acc += w.x * qs[d4 * 4 + 0] + w.y * qs[d4 * 4 + 1] +
                   w.z * qs[d4 * 4 + 2] + w.w * qs[d4 * 4 + 3];
        }
        rt[((size_t)b * C + c) * H + h] = acc * 0.125f;
    }
    if (threadIdx.x == 0) {
        float acc = 0.f;
        for (int d = 0; d < D; ++d) acc += bkv[h * D + d] * qs[d];
        cc[b * H + h] = acc * 0.125f;
    }
}

// scores[b][h][t] = cc[b][h] + sum_c x~[b][t][c] * rt[b][c][h]
// One wave per block; lane = t. rt/cc/fdiv are wave-uniform -> scalar loads.
__global__ void __launch_bounds__(64) k_scores(const float* __restrict__ x,
                                               const float* __restrict__ rt,
                                               const float* __restrict__ cc,
                                               const double* __restrict__ fdiv,
                                               float* __restrict__ scores) {
    int b = blockIdx.x >> 7;             // 128 blocks per batch (T/64)
    int t0 = (blockIdx.x & 127) << 6;
    int t = t0 + threadIdx.x;
    const float4* xrow = (const float4*)(x + ((size_t)b * T + t) * C);
    const float* rb = rt + (size_t)b * C * H;
    const float* ccb = cc + b * H;
    double td = (double)t;
    float acc[H];
#pragma unroll
    for (int h = 0; h < H; ++h) acc[h] = ccb[h];
#pragma unroll 2
    for (int c4 = 0; c4 < C / 4; ++c4) {
        float4 xv = xrow[c4];
        float xt[4];
        const float* xvp = (const float*)&xv;
#pragma unroll
        for (int j = 0; j < 4; ++j) {
            int c = c4 * 4 + j;
            double rev = td * fdiv[c];
            double fr = rev - floor(rev);
            float ang = (float)fr * 6.283185307179586f;
            float pe = (j & 1) ? __cosf(ang) : __sinf(ang);
            xt[j] = xvp[j] + pe;
        }
#pragma unroll
        for (int j = 0; j < 4; ++j) {
            const float* rr = rb + (size_t)(c4 * 4 + j) * H;
#pragma unroll
            for (int h = 0; h < H; ++h)
                acc[h] += xt[j] * rr[h];
        }
    }
    float* sb = scores + (size_t)b * H * T;
#pragma unroll
    for (int h = 0; h < H; ++h)
        sb[(size_t)h * T + t0 + threadIdx.x] = acc[h];
}

// per (b,h): m = max_t scores, l = sum_t exp(s-m); store (m, 1/l)
__global__ void __launch_bounds__(256) k_stats(const float* __restrict__ scores,
                                               float* __restrict__ ml) {
    __shared__ float red[256];
    int bh = blockIdx.x;
    const float* s = scores + (size_t)bh * T;
    float m = -1e30f;
    for (int i = threadIdx.x; i < T; i += 256) m = fmaxf(m, s[i]);
    red[threadIdx.x] = m; __syncthreads();
    for (int st = 128; st > 0; st >>= 1) {
        if (threadIdx.x < st) red[threadIdx.x] = fmaxf(red[threadIdx.x], red[threadIdx.x + st]);
        __syncthreads();
    }
    m = red[0]; __syncthreads();
    float l = 0.f;
    for (int i = threadIdx.x; i < T; i += 256) l += __expf(s[i] - m);
    red[threadIdx.x] = l; __syncthreads();
    for (int st = 128; st > 0; st >>= 1) {
        if (threadIdx.x < st) red[threadIdx.x] += red[threadIdx.x + st];
        __syncthreads();
    }
    if (threadIdx.x == 0) { ml[bh * 2] = m; ml[bh * 2 + 1] = 1.0f / red[0]; }
}

// sacc[b][h][c] += sum_{t in chunk} p[b][h][t] * x~[b][t][c]
__global__ void __launch_bounds__(256) k_wsum(const float* __restrict__ x,
                                              const float* __restrict__ scores,
                                              const float* __restrict__ ml,
                                              const double* __restrict__ fdiv,
                                              float* __restrict__ sacc) {
    __shared__ float p_lds[32 * H];
    __shared__ float msh[H], ish[H];
    int b = blockIdx.x / NS;
    int ts = (blockIdx.x % NS) * (T / NS);
    if (threadIdx.x < H) {
        msh[threadIdx.x] = ml[(b * H + threadIdx.x) * 2];
        ish[threadIdx.x] = ml[(b * H + threadIdx.x) * 2 + 1];
    }
    __syncthreads();
    int c0 = threadIdx.x * 4;
    double fdd[4];
#pragma unroll
    for (int j = 0; j < 4; ++j) fdd[j] = fdiv[c0 + j];
    float acc[H][4];
#pragma unroll
    for (int h = 0; h < H; ++h)
#pragma unroll
        for (int j = 0; j < 4; ++j) acc[h][j] = 0.f;

    for (int tc = ts; tc < ts + T / NS; tc += 32) {
        // phase 1: p for this 32-t chunk, all heads
        int idx = threadIdx.x;
#pragma unroll
        for (int r = 0; r < 2; ++r, idx += 256) {
            int h = idx >> 5, tl = idx & 31;
            float sc = scores[(size_t)(b * H + h) * T + tc + tl];
            p_lds[tl * H + h] = __expf(sc - msh[h]) * ish[h];
        }
        __syncthreads();
        // phase 2: accumulate
        for (int tl = 0; tl < 32; ++tl) {
            int t = tc + tl;
            float4 xv = *(const float4*)(x + ((size_t)b * T + t) * C + c0);
            const float* xvp = (const float*)&xv;
            float xt[4];
            double td = (double)t;
#pragma unroll
            for (int j = 0; j < 4; ++j) {
                double rev = td * fdd[j];
                double fr = rev - floor(rev);
                float ang = (float)fr * 6.283185307179586f;
                float pe = (j & 1) ? __cosf(ang) : __sinf(ang);
                xt[j] = xvp[j] + pe;
            }
#pragma unroll
            for (int h = 0; h < H; ++h) {
                float p = p_lds[tl * H + h];
#pragma unroll
                for (int j = 0; j < 4; ++j) acc[h][j] += p * xt[j];
            }
        }
        __syncthreads();
    }
#pragma unroll
    for (int h = 0; h < H; ++h)
#pragma unroll
        for (int j = 0; j < 4; ++j)
            atomicAdd(&sacc[(size_t)(b * H + h) * C + c0 + j], acc[h][j]);
}

// y[b][cy] = bv[cy] + sum_c sacc[b][cy>>6][c] * Wv[c][cy]
__global__ void __launch_bounds__(256) k_y(const float* __restrict__ Wkv,
                                           const float* __restrict__ bkv,
                                           const float* __restrict__ sacc,
                                           float* __restrict__ y) {
    __shared__ float sl[4 * C];
    int b = blockIdx.x >> 2, cblk = blockIdx.x & 3;
    int h0 = cblk * 4;
    for (int i = threadIdx.x; i < 4 * C; i += 256)
        sl[i] = sacc[(size_t)(b * H + h0) * C + i];
    __syncthreads();
    int cy = cblk * 256 + threadIdx.x;
    int hl = threadIdx.x >> 6;
    float acc = bkv[C + cy];
    const float* sh = sl + hl * C;
#pragma unroll 4
    for (int c = 0; c < C; ++c)
        acc += sh[c] * Wkv[(size_t)c * (2 * C) + C + cy];
    y[b * C + cy] = acc;
}

// out[b][j] = bo[j] + sum_k y[b][k] * Wo[k][j]
__global__ void __launch_bounds__(256) k_out(const float* __restrict__ Wo,
                                             const float* __restrict__ bo,
                                             const float* __restrict__ y,
                                             float* __restrict__ out) {
    __shared__ float yl[C];
    int b = blockIdx.x >> 2, cblk = blockIdx.x & 3;
    for (int i = threadIdx.x; i < C; i += 256) yl[i] = y[b * C + i];
    __syncthreads();
    int j = cblk * 256 + threadIdx.x;
    float acc = bo[j];
#pragma unroll 4
    for (int k = 0; k < C; ++k)
        acc += yl[k] * Wo[(size_t)k * C + j];
    out[b * C + j] = acc;
}

extern "C" void kernel_launch(void* const* d_in, const int* in_sizes, int n_in,
                              void* d_out, int out_size, void* d_ws, size_t ws_size,
                              hipStream_t stream) {
    const float* x   = (const float*)d_in[0];
    const float* Wq  = (const float*)d_in[1];
    const float* bq  = (const float*)d_in[2];
    const float* Wkv = (const float*)d_in[3];
    const float* bkv = (const float*)d_in[4];
    const float* Wo  = (const float*)d_in[5];
    const float* bo  = (const float*)d_in[6];
    float* out = (float*)d_out;

    char* w = (char*)d_ws;
    double* fdiv  = (double*)w;                       // C doubles = 8 KB
    float* q      = (float*)(w + 8192);
    float* rt     = q + B * C;
    float* cc     = rt + (size_t)B * C * H;
    float* scores = cc + B * H;
    float* ml     = scores + (size_t)B * H * T;
    float* sacc   = ml + B * H * 2;
    float* y      = sacc + (size_t)B * H * C;

    k_fdiv<<<4, 256, 0, stream>>>(fdiv);
    k_q<<<B * 4, 256, 0, stream>>>(x, Wq, bq, q);
    k_rt<<<B * H, 256, 0, stream>>>(Wkv, bkv, q, rt, cc);
    k_scores<<<B * (T / 64), 64, 0, stream>>>(x, rt, cc, fdiv, scores);
    k_stats<<<B * H, 256, 0, stream>>>(scores, ml);
    hipMemsetAsync(sacc, 0, (size_t)B * H * C * sizeof(float), stream);
    k_wsum<<<B * NS, 256, 0, stream>>>(x, scores, ml, fdiv, sacc);
    k_y<<<B * 4, 256, 0, stream>>>(Wkv, bkv, sacc, y);
    k_out<<<B * 4, 256, 0, stream>>>(Wo, bo, y, out);
}

// Round 3
// 1264.669 us; speedup vs baseline: 1.0790x; 1.0790x over previous
//
#include <hip/hip_runtime.h>
#include <math.h>

#define B 16
#define T 8192
#define C 1024
#define H 16
#define D 64
#define NS 32   // t-chunks for weighted-sum pass

typedef unsigned short ushort_t;
typedef unsigned int uint_t;

// ---------------------------------------------------------------------------
// Workspace layout:
//   xb     : bf16[B*T*C]    x + PE, materialized in bf16 (268 MB) -- FIRST for alignment
//   fdiv   : double[C]      div_term[pair]/(2*pi)
//   q      : B*C
//   rt     : B*C*H          Wk^T q per (b,c,h), scaled 1/8
//   cc     : B*H            bk.q per (b,h), scaled 1/8
//   scores : B*H*T
//   ml     : B*H*2          (max, 1/sum)
//   sacc   : B*H*C          softmax-weighted sum of x~
//   y      : B*C
// ---------------------------------------------------------------------------

__device__ __forceinline__ ushort_t f2bf(float f) {
    uint_t u = __float_as_uint(f);
    u = (u + 0x7FFFu + ((u >> 16) & 1u)) >> 16;   // round-to-nearest-even
    return (ushort_t)u;
}
__device__ __forceinline__ float bf2f(ushort_t h) {
    return __uint_as_float(((uint_t)h) << 16);
}

__global__ void k_fdiv(double* __restrict__ fdiv) {
    int c = blockIdx.x * 256 + threadIdx.x;
    if (c < C) {
        int i2 = c & ~1;
        double e = exp((double)i2 * (-9.210340371976184 / 1024.0)); // -ln(10000)/C
        fdiv[c] = e * 0.15915494309189535;                          // /(2*pi)
    }
}

// q[b][c] = bq[c] + sum_k x~[b,0,k] * Wq[k][c]   (PE(0,k) = k odd ? 1 : 0)
// grid B*16; block: 64 cols x 4 k-groups
__global__ void __launch_bounds__(256) k_q(const float* __restrict__ x,
                                           const float* __restrict__ Wq,
                                           const float* __restrict__ bq,
                                           float* __restrict__ q) {
    __shared__ float xs[C];
    __shared__ float red[4][64];
    int b = blockIdx.x >> 4;
    int cblk = blockIdx.x & 15;
    const float* xrow = x + (size_t)b * T * C;
    for (int i = threadIdx.x; i < C; i += 256)
        xs[i] = xrow[i] + ((i & 1) ? 1.0f : 0.0f);
    __syncthreads();
    int col = threadIdx.x & 63;
    int kg  = threadIdx.x >> 6;
    int c = cblk * 64 + col;
    float acc = 0.f;
#pragma unroll 8
    for (int k = kg * 256; k < kg * 256 + 256; ++k)
        acc += xs[k] * Wq[(size_t)k * C + c];
    red[kg][col] = acc;
    __syncthreads();
    if (kg == 0)
        q[b * C + c] = bq[c] + red[0][col] + red[1][col] + red[2][col] + red[3][col];
}

// rt[b][c][h] = 0.125 * sum_d Wkv[c][h*64+d] * q[b][h*64+d]
__global__ void __launch_bounds__(256) k_rt(const float* __restrict__ Wkv,
                                            const float* __restrict__ bkv,
                                            const float* __restrict__ q,
                                            float* __restrict__ rt,
                                            float* __restrict__ cc) {
    __shared__ float qs[D];
    int b = blockIdx.x >> 4, h = blockIdx.x & 15;
    if (threadIdx.x < D) qs[threadIdx.x] = q[b * C + h * D + threadIdx.x];
    __syncthreads();
    for (int c = threadIdx.x; c < C; c += 256) {
        const float4* wrow = (const float4*)(Wkv + (size_t)c * (2 * C) + h * D);
        float acc = 0.f;
#pragma unroll
        for (int d4 = 0; d4 < D / 4; ++d4) {
            float4 w = wrow[d4];
            acc += w.x * qs[d4 * 4 + 0] + w.y * qs[d4 * 4 + 1] +
                   w.z * qs[d4 * 4 + 2] + w.w * qs[d4 * 4 + 3];
        }
        rt[((size_t)b * C + c) * H + h] = acc * 0.125f;
    }
    if (threadIdx.x == 0) {
        float acc = 0.f;
        for (int d = 0; d < D; ++d) acc += bkv[h * D + d] * qs[d];
        cc[b * H + h] = acc * 0.125f;
    }
}

// Fused: scores[b][h][t] = cc + sum_c x~ * rt  AND  xb = bf16(x~)
// One wave per block; lane = t (per-lane row streaming, L1-line reuse).
__global__ void __launch_bounds__(64) k_score_pe(const float* __restrict__ x,
                                                 const float* __restrict__ rt,
                                                 const float* __restrict__ cc,
                                                 const double* __restrict__ fdiv,
                                                 float* __restrict__ scores,
                                                 ushort_t* __restrict__ xb) {
    int b = blockIdx.x >> 7;             // 128 blocks per batch (T/64)
    int t0 = (blockIdx.x & 127) << 6;
    int t = t0 + threadIdx.x;
    const float4* xrow = (const float4*)(x + ((size_t)b * T + t) * C);
    ushort_t* xbrow = xb + ((size_t)b * T + t) * C;
    const float* rb = rt + (size_t)b * C * H;
    const float* ccb = cc + b * H;
    double td = (double)t;
    float acc[H];
#pragma unroll
    for (int h = 0; h < H; ++h) acc[h] = ccb[h];
#pragma unroll 2
    for (int c4 = 0; c4 < C / 4; ++c4) {
        float4 xv = xrow[c4];
        const float* xvp = (const float*)&xv;
        float xt[4];
        // pairs (0,1) and (2,3) share an angle: pe = {sin a0, cos a0, sin a1, cos a1}
#pragma unroll
        for (int pr = 0; pr < 2; ++pr) {
            double rev = td * fdiv[c4 * 4 + pr * 2];
            double fr = rev - floor(rev);
            float ang = (float)fr * 6.283185307179586f;
            xt[pr * 2 + 0] = xvp[pr * 2 + 0] + __sinf(ang);
            xt[pr * 2 + 1] = xvp[pr * 2 + 1] + __cosf(ang);
        }
#pragma unroll
        for (int j = 0; j < 4; ++j) {
            const float* rr = rb + (size_t)(c4 * 4 + j) * H;
#pragma unroll
            for (int h = 0; h < H; ++h)
                acc[h] += xt[j] * rr[h];
        }
        uint2 pk;
        pk.x = (uint_t)f2bf(xt[0]) | ((uint_t)f2bf(xt[1]) << 16);
        pk.y = (uint_t)f2bf(xt[2]) | ((uint_t)f2bf(xt[3]) << 16);
        *(uint2*)(xbrow + c4 * 4) = pk;
    }
    float* sb = scores + (size_t)b * H * T;
#pragma unroll
    for (int h = 0; h < H; ++h)
        sb[(size_t)h * T + t0 + threadIdx.x] = acc[h];
}

// per (b,h): m = max_t scores, l = sum_t exp(s-m); store (m, 1/l)
__global__ void __launch_bounds__(256) k_stats(const float* __restrict__ scores,
                                               float* __restrict__ ml) {
    __shared__ float red[256];
    int bh = blockIdx.x;
    const float* s = scores + (size_t)bh * T;
    float m = -1e30f;
    for (int i = threadIdx.x; i < T; i += 256) m = fmaxf(m, s[i]);
    red[threadIdx.x] = m; __syncthreads();
    for (int st = 128; st > 0; st >>= 1) {
        if (threadIdx.x < st) red[threadIdx.x] = fmaxf(red[threadIdx.x], red[threadIdx.x + st]);
        __syncthreads();
    }
    m = red[0]; __syncthreads();
    float l = 0.f;
    for (int i = threadIdx.x; i < T; i += 256) l += __expf(s[i] - m);
    red[threadIdx.x] = l; __syncthreads();
    for (int st = 128; st > 0; st >>= 1) {
        if (threadIdx.x < st) red[threadIdx.x] += red[threadIdx.x + st];
        __syncthreads();
    }
    if (threadIdx.x == 0) { ml[bh * 2] = m; ml[bh * 2 + 1] = 1.0f / red[0]; }
}

// sacc[b][h][c] += sum_{t in chunk} p[b][h][t] * x~bf16[b][t][c]
__global__ void __launch_bounds__(256) k_wsum_bf(const ushort_t* __restrict__ xb,
                                                 const float* __restrict__ scores,
                                                 const float* __restrict__ ml,
                                                 float* __restrict__ sacc) {
    __shared__ float p_lds[32 * H];
    __shared__ float msh[H], ish[H];
    int b = blockIdx.x / NS;
    int ts = (blockIdx.x % NS) * (T / NS);
    if (threadIdx.x < H) {
        msh[threadIdx.x] = ml[(b * H + threadIdx.x) * 2];
        ish[threadIdx.x] = ml[(b * H + threadIdx.x) * 2 + 1];
    }
    __syncthreads();
    int c0 = threadIdx.x * 4;
    float acc[H][4];
#pragma unroll
    for (int h = 0; h < H; ++h)
#pragma unroll
        for (int j = 0; j < 4; ++j) acc[h][j] = 0.f;

    for (int tc = ts; tc < ts + T / NS; tc += 32) {
        int idx = threadIdx.x;
#pragma unroll
        for (int r = 0; r < 2; ++r, idx += 256) {
            int h = idx >> 5, tl = idx & 31;
            float sc = scores[(size_t)(b * H + h) * T + tc + tl];
            p_lds[tl * H + h] = __expf(sc - msh[h]) * ish[h];
        }
        __syncthreads();
#pragma unroll 2
        for (int tl = 0; tl < 32; ++tl) {
            int tt = tc + tl;
            uint2 xv = *(const uint2*)(xb + ((size_t)b * T + tt) * C + c0);
            float xt[4];
            xt[0] = bf2f((ushort_t)(xv.x & 0xFFFF));
            xt[1] = bf2f((ushort_t)(xv.x >> 16));
            xt[2] = bf2f((ushort_t)(xv.y & 0xFFFF));
            xt[3] = bf2f((ushort_t)(xv.y >> 16));
#pragma unroll
            for (int h = 0; h < H; ++h) {
                float p = p_lds[tl * H + h];
#pragma unroll
                for (int j = 0; j < 4; ++j) acc[h][j] += p * xt[j];
            }
        }
        __syncthreads();
    }
#pragma unroll
    for (int h = 0; h < H; ++h)
#pragma unroll
        for (int j = 0; j < 4; ++j)
            atomicAdd(&sacc[(size_t)(b * H + h) * C + c0 + j], acc[h][j]);
}

// y[b][h*64+col] = bv[...] + sum_c sacc[b][h][c] * Wv[c][h*64+col]
// grid B*16 (block = one head); 64 cols x 4 k-groups
__global__ void __launch_bounds__(256) k_y(const float* __restrict__ Wkv,
                                           const float* __restrict__ bkv,
                                           const float* __restrict__ sacc,
                                           float* __restrict__ y) {
    __shared__ float sl[C];
    __shared__ float red[4][64];
    int b = blockIdx.x >> 4, h = blockIdx.x & 15;
    for (int i = threadIdx.x; i < C; i += 256)
        sl[i] = sacc[(size_t)(b * H + h) * C + i];
    __syncthreads();
    int col = threadIdx.x & 63;
    int kg  = threadIdx.x >> 6;
    int cy = h * 64 + col;
    float acc = 0.f;
#pragma unroll 8
    for (int c = kg * 256; c < kg * 256 + 256; ++c)
        acc += sl[c] * Wkv[(size_t)c * (2 * C) + C + cy];
    red[kg][col] = acc;
    __syncthreads();
    if (kg == 0)
        y[b * C + cy] = bkv[C + cy] + red[0][col] + red[1][col] + red[2][col] + red[3][col];
}

// out[b][j] = bo[j] + sum_k y[b][k] * Wo[k][j];  grid B*16
__global__ void __launch_bounds__(256) k_out(const float* __restrict__ Wo,
                                             const float* __restrict__ bo,
                                             const float* __restrict__ y,
                                             float* __restrict__ out) {
    __shared__ float yl[C];
    __shared__ float red[4][64];
    int b = blockIdx.x >> 4, jb = blockIdx.x & 15;
    for (int i = threadIdx.x; i < C; i += 256) yl[i] = y[b * C + i];
    __syncthreads();
    int col = threadIdx.x & 63;
    int kg  = threadIdx.x >> 6;
    int j = jb * 64 + col;
    float acc = 0.f;
#pragma unroll 8
    for (int k = kg * 256; k < kg * 256 + 256; ++k)
        acc += yl[k] * Wo[(size_t)k * C + j];
    red[kg][col] = acc;
    __syncthreads();
    if (kg == 0)
        out[b * C + j] = bo[j] + red[0][col] + red[1][col] + red[2][col] + red[3][col];
}

extern "C" void kernel_launch(void* const* d_in, const int* in_sizes, int n_in,
                              void* d_out, int out_size, void* d_ws, size_t ws_size,
                              hipStream_t stream) {
    const float* x   = (const float*)d_in[0];
    const float* Wq  = (const float*)d_in[1];
    const float* bq  = (const float*)d_in[2];
    const float* Wkv = (const float*)d_in[3];
    const float* bkv = (const float*)d_in[4];
    const float* Wo  = (const float*)d_in[5];
    const float* bo  = (const float*)d_in[6];
    float* out = (float*)d_out;

    char* w = (char*)d_ws;
    ushort_t* xb  = (ushort_t*)w;                                  // 268 MB, 16B-aligned
    size_t xb_bytes = (size_t)B * T * C * sizeof(ushort_t);
    double* fdiv  = (double*)(w + xb_bytes);
    float* q      = (float*)(w + xb_bytes + 8192);
    float* rt     = q + B * C;
    float* cc     = rt + (size_t)B * C * H;
    float* scores = cc + B * H;
    float* ml     = scores + (size_t)B * H * T;
    float* sacc   = ml + B * H * 2;
    float* y      = sacc + (size_t)B * H * C;

    k_fdiv<<<4, 256, 0, stream>>>(fdiv);
    k_q<<<B * 16, 256, 0, stream>>>(x, Wq, bq, q);
    k_rt<<<B * H, 256, 0, stream>>>(Wkv, bkv, q, rt, cc);
    k_score_pe<<<B * (T / 64), 64, 0, stream>>>(x, rt, cc, fdiv, scores, xb);
    k_stats<<<B * H, 256, 0, stream>>>(scores, ml);
    hipMemsetAsync(sacc, 0, (size_t)B * H * C * sizeof(float), stream);
    k_wsum_bf<<<B * NS, 256, 0, stream>>>(xb, scores, ml, sacc);
    k_y<<<B * 16, 256, 0, stream>>>(Wkv, bkv, sacc, y);
    k_out<<<B * 16, 256, 0, stream>>>(Wo, bo, y, out);
}